// Round 2
// baseline (352.492 us; speedup 1.0000x reference)
//
#include <hip/hip_runtime.h>
#include <hip/hip_cooperative_groups.h>
#include <math.h>

namespace cg = cooperative_groups;

#define NB 4
#define NN 256
#define MAT (NN*NN)      // 65536
#define BMAT (NB*MAT)    // 262144
#define ALPHA 0.2f

__device__ __forceinline__ float wave_sum(float v) {
#pragma unroll
    for (int o = 32; o > 0; o >>= 1) v += __shfl_down(v, o, 64);
    return v;
}
__device__ __forceinline__ float wave_max(float v) {
#pragma unroll
    for (int o = 32; o > 0; o >>= 1) v = fmaxf(v, __shfl_down(v, o, 64));
    return v;
}
__device__ __forceinline__ float block_sum256(float v, volatile float* red) {
    int lane = threadIdx.x & 63, w = threadIdx.x >> 6;
    v = wave_sum(v);
    __syncthreads();
    if (lane == 0) red[w] = v;
    __syncthreads();
    return red[0] + red[1] + red[2] + red[3];
}
__device__ __forceinline__ float block_max256(float v, volatile float* red) {
    int lane = threadIdx.x & 63, w = threadIdx.x >> 6;
    v = wave_max(v);
    __syncthreads();
    if (lane == 0) red[w] = v;
    __syncthreads();
    return fmaxf(fmaxf(red[0], red[1]), fmaxf(red[2], red[3]));
}

// 32x32 output tile of C = A@W + bias, A,W,C are 256x256 row-major (per batch)
__device__ void gemm32(const float* __restrict__ A, const float* __restrict__ W,
                       const float* __restrict__ bias, float* __restrict__ C,
                       int ti, int tj, float* sm) {
    int tid = threadIdx.x;
    int tx = tid & 15, ty = tid >> 4;
    float* As = sm;        // [32][17]
    float* Bs = sm + 544;  // [16][33]
    int r0 = ti * 32, c0 = tj * 32;
    int ar = tid >> 3, ak = (tid & 7) * 2;
    int br = tid >> 4, bc2 = (tid & 15) * 2;
    float a00 = 0, a01 = 0, a10 = 0, a11 = 0;
    for (int k0 = 0; k0 < NN; k0 += 16) {
        float2 av = *reinterpret_cast<const float2*>(&A[(r0 + ar) * NN + k0 + ak]);
        As[ar * 17 + ak] = av.x; As[ar * 17 + ak + 1] = av.y;
        float2 bv = *reinterpret_cast<const float2*>(&W[(k0 + br) * NN + c0 + bc2]);
        Bs[br * 33 + bc2] = bv.x; Bs[br * 33 + bc2 + 1] = bv.y;
        __syncthreads();
#pragma unroll
        for (int k = 0; k < 16; ++k) {
            float al = As[ty * 17 + k], ah = As[(ty + 16) * 17 + k];
            float bl = Bs[k * 33 + tx], bh = Bs[k * 33 + tx + 16];
            a00 += al * bl; a01 += al * bh; a10 += ah * bl; a11 += ah * bh;
        }
        __syncthreads();
    }
    C[(r0 + ty) * NN + c0 + tx]           = a00 + bias[c0 + tx];
    C[(r0 + ty) * NN + c0 + tx + 16]      = a01 + bias[c0 + tx + 16];
    C[(r0 + ty + 16) * NN + c0 + tx]      = a10 + bias[c0 + tx];
    C[(r0 + ty + 16) * NN + c0 + tx + 16] = a11 + bias[c0 + tx + 16];
}

__global__ __launch_bounds__(256) void gat_fused(
    const float* __restrict__ edges,
    const float* __restrict__ wp0, const float* __restrict__ bp0,
    const float* __restrict__ ae0, const float* __restrict__ wa0, const float* __restrict__ ba0,
    const float* __restrict__ wp1, const float* __restrict__ bp1,
    const float* __restrict__ ae1, const float* __restrict__ wa1, const float* __restrict__ ba1,
    float* __restrict__ out, float* __restrict__ ws)
{
    cg::grid_group grid = cg::this_grid();
    __shared__ float sm[1632];
    __shared__ float red[4];
    float* E   = ws;
    float* G   = ws + 1 * BMAT;
    float* H   = ws + 2 * BMAT;
    float* Adj = ws + 3 * BMAT;
    float* eLv = ws + 4 * BMAT;
    float* eHv = ws + 5 * BMAT;
    float* F   = ws + 6 * BMAT;
    float* cnt = ws + 7 * BMAT;       // NB*NN
    float* rs  = cnt + NB * NN;       // NB*NN

    const int bid = blockIdx.x, tid = threadIdx.x;
    const int tx = tid & 15, ty = tid >> 4;
    const float* Ecur = edges;

    for (int l = 0; l < 2; ++l) {
        const float* wpl = l ? wp1 : wp0;
        const float* bpl = l ? bp1 : bp0;
        const float* ael = l ? ae1 : ae0;
        const float* wal = l ? wa1 : wa0;
        const float* bal = l ? ba1 : ba0;

        // ---- P1: G = Ecur@wa+ba ; H = Ecur@wp+bp  (512 tile jobs) ----
        for (int job = bid; job < 512; job += 256) {
            int m = job >> 8;
            int b = (job >> 6) & 3;
            int t = job & 63;
            gemm32(Ecur + b * MAT, m ? wpl : wal, m ? bpl : bal,
                   (m ? H : G) + b * MAT, t >> 3, t & 7, sm);
        }
        grid.sync();

        // ---- P2: adjacency + row transform (4 rows per block) ----
        float S;
        {
            float sv = ael[tid] + ael[tid + 256];
            S = block_sum256(sv, red);
        }
        for (int j2 = 0; j2 < 4; ++j2) {
            int row = bid * 4 + j2;       // 0..1023
            int b = row >> 8, i = row & 255;
            const float* Gb = G + b * MAT;
            float g1 = Gb[i * NN + tid];
            float g2 = Gb[tid * NN + i];
            float s = 0.5f * (1.f / (1.f + expf(-g1)) + 1.f / (1.f + expf(-g2)));
            float av = (s > 0.5f) ? 1.f : 0.f;
            Adj[b * MAT + i * NN + tid] = av;
            float c = block_sum256(av, red);
            if (tid == 0) cnt[b * NN + i] = c;

            float h = H[b * MAT + i * NN + tid];
            float x = S * h;
            float L = (x > 0.f) ? x : ALPHA * x;
            float M = block_max256(L, red);
            float e = expf(L - M);
            eLv[b * MAT + i * NN + tid] = e;
            eHv[b * MAT + i * NN + tid] = e * h;
            float hs = block_sum256(h, red);
            if (tid == 0) rs[b * NN + i] = hs;
        }
        grid.sync();

        // ---- P3: D/Num GEMMs vs Adj^T, fused divide + fallback -> F ----
        {
            int b = bid >> 6, t = bid & 63;
            int kr0 = (t >> 3) * 32, i0 = (t & 7) * 32;
            const float* La = eLv + b * MAT;
            const float* Ha = eHv + b * MAT;
            const float* Ab = Adj + b * MAT;
            float* Ls = sm;
            float* Hs = sm + 544;
            float* Asb = sm + 1088;
            int ar = tid >> 3, ak = (tid & 7) * 2;
            float d00 = 0, d01 = 0, d10 = 0, d11 = 0;
            float n00 = 0, n01 = 0, n10 = 0, n11 = 0;
            for (int j0 = 0; j0 < NN; j0 += 16) {
                float2 lv = *reinterpret_cast<const float2*>(&La[(kr0 + ar) * NN + j0 + ak]);
                Ls[ar * 17 + ak] = lv.x; Ls[ar * 17 + ak + 1] = lv.y;
                float2 hv = *reinterpret_cast<const float2*>(&Ha[(kr0 + ar) * NN + j0 + ak]);
                Hs[ar * 17 + ak] = hv.x; Hs[ar * 17 + ak + 1] = hv.y;
                float2 avv = *reinterpret_cast<const float2*>(&Ab[(i0 + ar) * NN + j0 + ak]);
                Asb[ar * 17 + ak] = avv.x; Asb[ar * 17 + ak + 1] = avv.y;
                __syncthreads();
#pragma unroll
                for (int jj = 0; jj < 16; ++jj) {
                    float al = Ls[ty * 17 + jj], ah = Ls[(ty + 16) * 17 + jj];
                    float hl = Hs[ty * 17 + jj], hh = Hs[(ty + 16) * 17 + jj];
                    float wl = Asb[tx * 17 + jj], wh = Asb[(tx + 16) * 17 + jj];
                    d00 += al * wl; d01 += al * wh; d10 += ah * wl; d11 += ah * wh;
                    n00 += hl * wl; n01 += hl * wh; n10 += hh * wl; n11 += hh * wh;
                }
                __syncthreads();
            }
            float c0v = cnt[b * NN + i0 + tx], c1v = cnt[b * NN + i0 + tx + 16];
            float r0v = rs[b * NN + kr0 + ty] * (1.f / 256.f);
            float r1v = rs[b * NN + kr0 + ty + 16] * (1.f / 256.f);
            float* Fb = F + b * MAT;
            Fb[(kr0 + ty) * NN + i0 + tx]            = (c0v > 0.5f) ? n00 / d00 : r0v;
            Fb[(kr0 + ty) * NN + i0 + tx + 16]       = (c1v > 0.5f) ? n01 / d01 : r0v;
            Fb[(kr0 + ty + 16) * NN + i0 + tx]       = (c0v > 0.5f) ? n10 / d10 : r1v;
            Fb[(kr0 + ty + 16) * NN + i0 + tx + 16]  = (c1v > 0.5f) ? n11 / d11 : r1v;
        }
        grid.sync();

        // ---- P4: E = 0.5*(F + F^T) via LDS tile transpose ----
        {
            int b = bid >> 6, t = bid & 63;
            int ti = t >> 3, tj = t & 7;
            const float* Fb = F + b * MAT;
            float* T = sm;  // [32][33]
#pragma unroll
            for (int p = 0; p < 2; ++p)
#pragma unroll
                for (int q = 0; q < 2; ++q)
                    T[(ty + 16 * p) * 33 + tx + 16 * q] =
                        Fb[(tj * 32 + ty + 16 * p) * NN + ti * 32 + tx + 16 * q];
            __syncthreads();
            float* Eb = E + b * MAT;
#pragma unroll
            for (int p = 0; p < 2; ++p)
#pragma unroll
                for (int q = 0; q < 2; ++q) {
                    int rr = ty + 16 * p, cc = tx + 16 * q;
                    Eb[(ti * 32 + rr) * NN + tj * 32 + cc] =
                        0.5f * (Fb[(ti * 32 + rr) * NN + tj * 32 + cc] + T[cc * 33 + rr]);
                }
            __syncthreads();
        }
        grid.sync();
        Ecur = E;
    }

    // ---- P5: out = tanh(E), duplicated (reference returns (out, out)) ----
    for (int idx = bid * 256 + tid; idx < BMAT; idx += 65536) {
        float tv = tanhf(E[idx]);
        out[idx] = tv;
        out[BMAT + idx] = tv;
    }
}

extern "C" void kernel_launch(void* const* d_in, const int* in_sizes, int n_in,
                              void* d_out, int out_size, void* d_ws, size_t ws_size,
                              hipStream_t stream) {
    const float* edges = (const float*)d_in[1];
    const float* wp0 = (const float*)d_in[7];
    const float* bp0 = (const float*)d_in[8];
    const float* ae0 = (const float*)d_in[9];
    const float* wa0 = (const float*)d_in[10];
    const float* ba0 = (const float*)d_in[11];
    const float* wp1 = (const float*)d_in[17];
    const float* bp1 = (const float*)d_in[18];
    const float* ae1 = (const float*)d_in[19];
    const float* wa1 = (const float*)d_in[20];
    const float* ba1 = (const float*)d_in[21];
    float* out = (float*)d_out;
    float* ws = (float*)d_ws;

    void* args[] = {&edges, &wp0, &bp0, &ae0, &wa0, &ba0,
                    &wp1, &bp1, &ae1, &wa1, &ba1, &out, &ws};
    hipLaunchCooperativeKernel((const void*)gat_fused, dim3(256), dim3(256),
                               args, 0, stream);
}

// Round 3
// 102.532 us; speedup vs baseline: 3.4379x; 3.4379x over previous
//
#include <hip/hip_runtime.h>
#include <math.h>

#define NB 4
#define NN 256
#define MAT (NN*NN)      // 65536
#define BMAT (NB*MAT)    // 262144
#define ALPHA 0.2f

__device__ __forceinline__ float wave_sum(float v) {
#pragma unroll
    for (int o = 32; o > 0; o >>= 1) v += __shfl_down(v, o, 64);
    return v;
}
__device__ __forceinline__ float wave_max(float v) {
#pragma unroll
    for (int o = 32; o > 0; o >>= 1) v = fmaxf(v, __shfl_down(v, o, 64));
    return v;
}
__device__ __forceinline__ float block_sum256(float v, volatile float* red) {
    int lane = threadIdx.x & 63, w = threadIdx.x >> 6;
    v = wave_sum(v);
    __syncthreads();
    if (lane == 0) red[w] = v;
    __syncthreads();
    return red[0] + red[1] + red[2] + red[3];
}
__device__ __forceinline__ float block_max256(float v, volatile float* red) {
    int lane = threadIdx.x & 63, w = threadIdx.x >> 6;
    v = wave_max(v);
    __syncthreads();
    if (lane == 0) red[w] = v;
    __syncthreads();
    return fmaxf(fmaxf(red[0], red[1]), fmaxf(red[2], red[3]));
}

// ---- K1: G = E@wa+ba and H = E@wp+bp in one launch. 512 blocks.
// bid: m=bid>>8 (0:G 1:H), b=(bid>>6)&3, tile t=bid&63 -> (t>>3, t&7)
__global__ __launch_bounds__(256) void k_gemm2(
    const float* __restrict__ A,
    const float* __restrict__ Wg, const float* __restrict__ bg,
    const float* __restrict__ Wh, const float* __restrict__ bhp,
    float* __restrict__ G, float* __restrict__ H)
{
    __shared__ float As[32 * 17], Bs[16 * 33];
    int bid = blockIdx.x;
    int m = bid >> 8, b = (bid >> 6) & 3, t = bid & 63;
    const float* W = m ? Wh : Wg;
    const float* bias = m ? bhp : bg;
    float* C = (m ? H : G) + b * MAT;
    const float* Ab = A + b * MAT;
    int r0 = (t >> 3) * 32, c0 = (t & 7) * 32;
    int tid = threadIdx.x, tx = tid & 15, ty = tid >> 4;
    int ar = tid >> 3, ak = (tid & 7) * 2;
    int br = tid >> 4, bc = (tid & 15) * 2;
    float a00 = 0, a01 = 0, a10 = 0, a11 = 0;
    for (int k0 = 0; k0 < NN; k0 += 16) {
        float2 av = *(const float2*)&Ab[(r0 + ar) * NN + k0 + ak];
        As[ar * 17 + ak] = av.x; As[ar * 17 + ak + 1] = av.y;
        float2 bv = *(const float2*)&W[(k0 + br) * NN + c0 + bc];
        Bs[br * 33 + bc] = bv.x; Bs[br * 33 + bc + 1] = bv.y;
        __syncthreads();
#pragma unroll
        for (int k = 0; k < 16; ++k) {
            float al = As[ty * 17 + k], ah = As[(ty + 16) * 17 + k];
            float bl = Bs[k * 33 + tx], bh2 = Bs[k * 33 + tx + 16];
            a00 += al * bl; a01 += al * bh2; a10 += ah * bl; a11 += ah * bh2;
        }
        __syncthreads();
    }
    C[(r0 + ty) * NN + c0 + tx]           = a00 + bias[c0 + tx];
    C[(r0 + ty) * NN + c0 + tx + 16]      = a01 + bias[c0 + tx + 16];
    C[(r0 + ty + 16) * NN + c0 + tx]      = a10 + bias[c0 + tx];
    C[(r0 + ty + 16) * NN + c0 + tx + 16] = a11 + bias[c0 + tx + 16];
}

// ---- K2: adjacency + cnt + row transform (eL, eH, rs). grid (NN, NB).
__global__ __launch_bounds__(256) void k_prep(
    const float* __restrict__ G, const float* __restrict__ H,
    const float* __restrict__ ae,
    float* __restrict__ Adj, float* __restrict__ eL, float* __restrict__ eH,
    float* __restrict__ cnt, float* __restrict__ rs)
{
    __shared__ float red[4];
    int b = blockIdx.y, i = blockIdx.x, j = threadIdx.x;
    float S = block_sum256(ae[j] + ae[j + 256], red);
    const float* Gb = G + b * MAT;
    float g1 = Gb[i * NN + j];
    float g2 = Gb[j * NN + i];
    float s = 0.5f * (1.f / (1.f + expf(-g1)) + 1.f / (1.f + expf(-g2)));
    float av = (s > 0.5f) ? 1.f : 0.f;
    Adj[b * MAT + i * NN + j] = av;
    float c = block_sum256(av, red);
    if (j == 0) cnt[b * NN + i] = c;
    float h = H[b * MAT + i * NN + j];
    float x = S * h;
    float L = (x > 0.f) ? x : ALPHA * x;
    float M = block_max256(L, red);
    float e = expf(L - M);
    eL[b * MAT + i * NN + j] = e;
    eH[b * MAT + i * NN + j] = e * h;
    float hs = block_sum256(h, red);
    if (j == 0) rs[b * NN + i] = hs;
}

// ---- K3: attn GEMM pair + divide/fallback + symmetrize (+optional tanh out).
// grid (36, NB): block handles tile pair (ti,tj), ti<=tj; writes E tiles
// (ti,tj) and (tj,ti).
template<int FINAL>
__global__ __launch_bounds__(256) void k_attn_sym(
    const float* __restrict__ eL, const float* __restrict__ eH,
    const float* __restrict__ Adj, const float* __restrict__ cnt,
    const float* __restrict__ rs, float* __restrict__ Eo)
{
    __shared__ float sm[6 * 544];          // 6 tiles [32][17]
    int b = blockIdx.y;
    int ti = 0, rem = blockIdx.x;
    while (rem >= 8 - ti) { rem -= 8 - ti; ++ti; }
    int tj = ti + rem;

    int tid = threadIdx.x, tx = tid & 15, ty = tid >> 4;
    int lr = tid >> 3, lc = (tid & 7) * 2;
    const float* eLb = eL + b * MAT;
    const float* eHb = eH + b * MAT;
    const float* Ajb = Adj + b * MAT;
    float* La = sm;           // eL rows ti
    float* Ha = sm + 544;     // eH rows ti
    float* Ka = sm + 1088;    // Adj rows ti
    float* Lb = sm + 1632;    // eL rows tj
    float* Hb = sm + 2176;    // eH rows tj
    float* Kb = sm + 2720;    // Adj rows tj

    float da00=0,da01=0,da10=0,da11=0, na00=0,na01=0,na10=0,na11=0;
    float db00=0,db01=0,db10=0,db11=0, nb00=0,nb01=0,nb10=0,nb11=0;
    int ra = (ti * 32 + lr) * NN, rb = (tj * 32 + lr) * NN;
    for (int j0 = 0; j0 < NN; j0 += 16) {
        float2 v;
        v = *(const float2*)&eLb[ra + j0 + lc]; La[lr*17+lc] = v.x; La[lr*17+lc+1] = v.y;
        v = *(const float2*)&eHb[ra + j0 + lc]; Ha[lr*17+lc] = v.x; Ha[lr*17+lc+1] = v.y;
        v = *(const float2*)&Ajb[ra + j0 + lc]; Ka[lr*17+lc] = v.x; Ka[lr*17+lc+1] = v.y;
        v = *(const float2*)&eLb[rb + j0 + lc]; Lb[lr*17+lc] = v.x; Lb[lr*17+lc+1] = v.y;
        v = *(const float2*)&eHb[rb + j0 + lc]; Hb[lr*17+lc] = v.x; Hb[lr*17+lc+1] = v.y;
        v = *(const float2*)&Ajb[rb + j0 + lc]; Kb[lr*17+lc] = v.x; Kb[lr*17+lc+1] = v.y;
        __syncthreads();
#pragma unroll
        for (int jj = 0; jj < 16; ++jj) {
            float lal = La[ty*17+jj], lah = La[(ty+16)*17+jj];
            float hal = Ha[ty*17+jj], hah = Ha[(ty+16)*17+jj];
            float kbl = Kb[tx*17+jj], kbh = Kb[(tx+16)*17+jj];
            da00 += lal*kbl; da01 += lal*kbh; da10 += lah*kbl; da11 += lah*kbh;
            na00 += hal*kbl; na01 += hal*kbh; na10 += hah*kbl; na11 += hah*kbh;
            float lbl = Lb[ty*17+jj], lbh = Lb[(ty+16)*17+jj];
            float hbl = Hb[ty*17+jj], hbh = Hb[(ty+16)*17+jj];
            float kal = Ka[tx*17+jj], kah = Ka[(tx+16)*17+jj];
            db00 += lbl*kal; db01 += lbl*kah; db10 += lbh*kal; db11 += lbh*kah;
            nb00 += hbl*kal; nb01 += hbl*kah; nb10 += hbh*kal; nb11 += hbh*kah;
        }
        __syncthreads();
    }

    // divide + all-masked fallback
    const float* cb = cnt + b * NN;
    const float* rsb = rs + b * NN;
    float ca0 = cb[tj*32+tx], ca1 = cb[tj*32+tx+16];
    float rav0 = rsb[ti*32+ty] * (1.f/256.f), rav1 = rsb[ti*32+ty+16] * (1.f/256.f);
    float Fa00 = (ca0>0.5f) ? na00/da00 : rav0;
    float Fa01 = (ca1>0.5f) ? na01/da01 : rav0;
    float Fa10 = (ca0>0.5f) ? na10/da10 : rav1;
    float Fa11 = (ca1>0.5f) ? na11/da11 : rav1;
    float cb0 = cb[ti*32+tx], cb1 = cb[ti*32+tx+16];
    float rbv0 = rsb[tj*32+ty] * (1.f/256.f), rbv1 = rsb[tj*32+ty+16] * (1.f/256.f);
    float Fb00 = (cb0>0.5f) ? nb00/db00 : rbv0;
    float Fb01 = (cb1>0.5f) ? nb01/db01 : rbv0;
    float Fb10 = (cb0>0.5f) ? nb10/db10 : rbv1;
    float Fb11 = (cb1>0.5f) ? nb11/db11 : rbv1;

    // symmetrize via LDS transpose of the partner tile
    __syncthreads();
    float* FsA = sm;            // [32][33]
    float* FsB = sm + 1056;
    FsA[ty*33+tx]=Fa00; FsA[ty*33+tx+16]=Fa01;
    FsA[(ty+16)*33+tx]=Fa10; FsA[(ty+16)*33+tx+16]=Fa11;
    FsB[ty*33+tx]=Fb00; FsB[ty*33+tx+16]=Fb01;
    FsB[(ty+16)*33+tx]=Fb10; FsB[(ty+16)*33+tx+16]=Fb11;
    __syncthreads();
    float ea00 = 0.5f*(Fa00 + FsB[tx*33+ty]);
    float ea01 = 0.5f*(Fa01 + FsB[(tx+16)*33+ty]);
    float ea10 = 0.5f*(Fa10 + FsB[tx*33+ty+16]);
    float ea11 = 0.5f*(Fa11 + FsB[(tx+16)*33+ty+16]);
    float eb00 = 0.5f*(Fb00 + FsA[tx*33+ty]);
    float eb01 = 0.5f*(Fb01 + FsA[(tx+16)*33+ty]);
    float eb10 = 0.5f*(Fb10 + FsA[tx*33+ty+16]);
    float eb11 = 0.5f*(Fb11 + FsA[(tx+16)*33+ty+16]);

    int base = b * MAT;
    int ia00 = base + (ti*32+ty)*NN + tj*32+tx;
    int ib00 = base + (tj*32+ty)*NN + ti*32+tx;
    if (FINAL) {
        float* o = Eo;
        float t00=tanhf(ea00), t01=tanhf(ea01), t10=tanhf(ea10), t11=tanhf(ea11);
        float u00=tanhf(eb00), u01=tanhf(eb01), u10=tanhf(eb10), u11=tanhf(eb11);
        o[ia00]=t00; o[BMAT+ia00]=t00;
        o[ia00+16]=t01; o[BMAT+ia00+16]=t01;
        o[ia00+16*NN]=t10; o[BMAT+ia00+16*NN]=t10;
        o[ia00+16*NN+16]=t11; o[BMAT+ia00+16*NN+16]=t11;
        o[ib00]=u00; o[BMAT+ib00]=u00;
        o[ib00+16]=u01; o[BMAT+ib00+16]=u01;
        o[ib00+16*NN]=u10; o[BMAT+ib00+16*NN]=u10;
        o[ib00+16*NN+16]=u11; o[BMAT+ib00+16*NN+16]=u11;
    } else {
        Eo[ia00]=ea00; Eo[ia00+16]=ea01;
        Eo[ia00+16*NN]=ea10; Eo[ia00+16*NN+16]=ea11;
        Eo[ib00]=eb00; Eo[ib00+16]=eb01;
        Eo[ib00+16*NN]=eb10; Eo[ib00+16*NN+16]=eb11;
    }
}

extern "C" void kernel_launch(void* const* d_in, const int* in_sizes, int n_in,
                              void* d_out, int out_size, void* d_ws, size_t ws_size,
                              hipStream_t stream) {
    const float* edges = (const float*)d_in[1];
    const float* wp[2] = {(const float*)d_in[7],  (const float*)d_in[17]};
    const float* bp[2] = {(const float*)d_in[8],  (const float*)d_in[18]};
    const float* ae[2] = {(const float*)d_in[9],  (const float*)d_in[19]};
    const float* wa[2] = {(const float*)d_in[10], (const float*)d_in[20]};
    const float* ba[2] = {(const float*)d_in[11], (const float*)d_in[21]};
    float* out = (float*)d_out;

    float* ws  = (float*)d_ws;
    float* E   = ws + 0 * BMAT;
    float* G   = ws + 1 * BMAT;
    float* H   = ws + 2 * BMAT;
    float* Adj = ws + 3 * BMAT;
    float* eLv = ws + 4 * BMAT;
    float* eHv = ws + 5 * BMAT;
    float* cnt = ws + 6 * BMAT;       // NB*NN
    float* rs  = cnt + NB * NN;       // NB*NN

    const float* Ecur = edges;
    for (int l = 0; l < 2; ++l) {
        k_gemm2<<<512, 256, 0, stream>>>(Ecur, wa[l], ba[l], wp[l], bp[l], G, H);
        k_prep<<<dim3(NN, NB), 256, 0, stream>>>(G, H, ae[l], Adj, eLv, eHv, cnt, rs);
        if (l == 0)
            k_attn_sym<0><<<dim3(36, NB), 256, 0, stream>>>(eLv, eHv, Adj, cnt, rs, E);
        else
            k_attn_sym<1><<<dim3(36, NB), 256, 0, stream>>>(eLv, eHv, Adj, cnt, rs, out);
        Ecur = E;
    }
}